// Round 2
// baseline (40.190 us; speedup 1.0000x reference)
//
#include <hip/hip_runtime.h>
#include <cstdint>

// JAX >= 0.4.30 defaults jax_threefry_partitionable=True. If validation fails
// with large absmax, flip this to 0 (legacy split-halves counter scheme).
#define JAX_PARTITIONABLE 1

namespace {

constexpr int N    = 20000;   // nodes
constexpr int D    = 128;     // feature dim
constexpr int DEG  = 32;      // neighbors per node
constexpr int BB   = 1024;    // batch
constexpr int T    = 8;       // walk_times
constexpr int NW   = (N + 31) / 32;  // 625 mask words
constexpr int MAXC = 384;     // candidate-list bound (true max 32 + 8*32 + 1 = 289)

__device__ __forceinline__ uint32_t rotl32(uint32_t x, int n) {
  return (x << n) | (x >> (32 - n));
}

// Threefry-2x32, 20 rounds (Random123 / JAX threefry2x32_p).
__device__ __forceinline__ void threefry2x32(uint32_t k0, uint32_t k1,
                                             uint32_t x0, uint32_t x1,
                                             uint32_t& o0, uint32_t& o1) {
  const uint32_t ks2 = k0 ^ k1 ^ 0x1BD11BDAu;
  x0 += k0; x1 += k1;
#define TF_ROUND(r) { x0 += x1; x1 = rotl32(x1, (r)); x1 ^= x0; }
  TF_ROUND(13) TF_ROUND(15) TF_ROUND(26) TF_ROUND(6)
  x0 += k1;  x1 += ks2 + 1u;
  TF_ROUND(17) TF_ROUND(29) TF_ROUND(16) TF_ROUND(24)
  x0 += ks2; x1 += k0 + 2u;
  TF_ROUND(13) TF_ROUND(15) TF_ROUND(26) TF_ROUND(6)
  x0 += k0;  x1 += k1 + 3u;
  TF_ROUND(17) TF_ROUND(29) TF_ROUND(16) TF_ROUND(24)
  x0 += k1;  x1 += ks2 + 4u;
  TF_ROUND(13) TF_ROUND(15) TF_ROUND(26) TF_ROUND(6)
  x0 += ks2; x1 += k0 + 5u;
#undef TF_ROUND
  o0 = x0; o1 = x1;
}

// Exact emulation of jax.random.gumbel's f32 pipeline from 32 random bits.
// JAX _uniform: mant = bits >> (32-23) -- the TOP 23 bits (this was the bug);
//   u = (1.0f | mant) - 1.0f  == mant * 2^-23, or f32 tiny when mant==0.
// gumbel = -fl32(log( fl32(-log(u)) )); double log == correctly-rounded f32 log.
__device__ __forceinline__ float gumbel_f32(uint32_t bits) {
  const uint32_t mant = bits >> 9;
  const float u = (mant == 0u) ? 1.17549435e-38f
                               : (__uint_as_float(0x3F800000u | mant) - 1.0f);
  const float inner = -(float)log((double)u);
  return -(float)log((double)inner);
}

__global__ __launch_bounds__(64)
void walk_kernel(const float* __restrict__ features,
                 const float* __restrict__ W,
                 const float* __restrict__ bptr,
                 const int*   __restrict__ neighbors,
                 const int*   __restrict__ train_index,
                 int* __restrict__ out)
{
  __shared__ uint32_t mask0[NW];     // candidate membership, double-buffered
  __shared__ uint32_t mask1[NW];
  __shared__ uint32_t chosenM[NW];   // chosen (visited incl. self)
  __shared__ uint32_t adjM[NW];      // neighbors-of-new (set semantics)
  __shared__ int      lst[2][MAXC];
  __shared__ float    val[2][MAXC];
  __shared__ int      cnts[2];
  __shared__ int      adjList[DEG];
  __shared__ uint32_t skey[T][2];

  const int r    = blockIdx.x;
  const int lane = threadIdx.x;
  const int self = train_index[r];

  for (int i = lane; i < NW; i += 64) { mask0[i] = 0u; mask1[i] = 0u; chosenM[i] = 0u; }

  // Step keys: jax.random.split(key(42), 8)
  if (lane < T) {
#if JAX_PARTITIONABLE
    uint32_t o0, o1;
    threefry2x32(0u, 42u, 0u, (uint32_t)lane, o0, o1);
    skey[lane][0] = o0; skey[lane][1] = o1;
#else
    // legacy: counts=iota(16); x0=[0..7], x1=[8..15]; keys[k]=(flat[2k],flat[2k+1])
    const int i0 = (lane < 4) ? 2 * lane : 2 * (lane - 4);
    uint32_t a0, b0, a1, b1;
    threefry2x32(0u, 42u, (uint32_t)i0,       (uint32_t)(i0 + 8), a0, b0);
    threefry2x32(0u, 42u, (uint32_t)(i0 + 1), (uint32_t)(i0 + 9), a1, b1);
    if (lane < 4) { skey[lane][0] = a0; skey[lane][1] = a1; }
    else          { skey[lane][0] = b0; skey[lane][1] = b1; }
#endif
  }
  if (lane == 0) { cnts[0] = 0; cnts[1] = 0; }
  __syncthreads();

  // ---- step-0 scores: s_j = relu((sx + sy_j) + b) ----
  const float bval = bptr[0];
  const float* frow = features + (size_t)self * D;
  float acc = frow[lane] * W[lane] + frow[lane + 64] * W[lane + 64];
  for (int m = 1; m < 64; m <<= 1) acc += __shfl_xor(acc, m);
  const float sx = acc;   // identical across lanes

  int   nbj  = -1;
  float sval = 0.0f;
  if (lane < DEG) {
    nbj = neighbors[(size_t)self * DEG + lane];
    const float* g  = features + (size_t)nbj * D;
    const float* wy = W + D;
    float a = 0.0f;
    for (int d = 0; d < D; d += 4) {
      const float4 f = *reinterpret_cast<const float4*>(g + d);
      const float4 w = *reinterpret_cast<const float4*>(wy + d);
      a += f.x * w.x; a += f.y * w.y; a += f.z * w.z; a += f.w * w.w;
    }
    sval = fmaxf((sx + a) + bval, 0.0f);
  }
  // build step-0 candidate list: {c != self : s_c > 0}, dedup (dup nodes have identical s)
  if (lane < DEG && nbj != self && sval > 0.0f) {
    const uint32_t w = (uint32_t)nbj >> 5, bit = 1u << (nbj & 31);
    const uint32_t old = atomicOr(&mask0[w], bit);
    if (!(old & bit)) {
      const int p = atomicAdd(&cnts[0], 1);
      if (p < MAXC) { lst[0][p] = nbj; val[0][p] = sval; }
    }
  }
  __syncthreads();
  if (lane == 0) {
    chosenM[(uint32_t)self >> 5] |= 1u << (self & 31);   // chosen = self_oh
    if (cnts[0] == 0) {  // pre-scan fallback mutates the carry: candi = self_oh
      lst[0][0] = self; val[0][0] = 1.0f; cnts[0] = 1;
      mask0[(uint32_t)self >> 5] |= 1u << (self & 31);
    }
  }
  __syncthreads();

  int cur = 0;
  for (int k = 0; k < T; ++k) {
    const int cnt = cnts[cur];
    const uint32_t kk0 = skey[k][0], kk1 = skey[k][1];
    int newNode;
    if (cnt == 0) {
      // in-step fallback: p = self_oh (argmax is trivially self); carry untouched
      newNode = self;
    } else {
      float bestV = -__builtin_huge_valf();
      int   bestC = 0x7FFFFFFF;
      for (int i = lane; i < cnt; i += 64) {
        const int c = lst[cur][i];
        const uint32_t j = (uint32_t)(r * N + c);  // flat index into (B, N)
        uint32_t o0, o1, bits;
#if JAX_PARTITIONABLE
        threefry2x32(kk0, kk1, 0u, j, o0, o1);
        bits = o0 ^ o1;
#else
        const uint32_t HALF = 10240000u;  // B*N/2
        if (j < HALF) { threefry2x32(kk0, kk1, j, j + HALF, o0, o1); bits = o0; }
        else          { threefry2x32(kk0, kk1, j - HALF, j, o0, o1); bits = o1; }
#endif
        const float gmb = gumbel_f32(bits);
        const float lp  = (float)log((double)val[cur][i]);  // log(1)=0 for steps>=1
        const float v   = lp + gmb;
        if (v > bestV || (v == bestV && c < bestC)) { bestV = v; bestC = c; }
      }
      // wave argmax; tie -> smallest column index (matches jnp.argmax first-occurrence)
      for (int m = 1; m < 64; m <<= 1) {
        const float ov = __shfl_xor(bestV, m);
        const int   oc = __shfl_xor(bestC, m);
        if (ov > bestV || (ov == bestV && oc < bestC)) { bestV = ov; bestC = oc; }
      }
      newNode = bestC;
    }
    if (lane == 0) out[r * (T + 1) + k + 1] = newNode;

    uint32_t* const oldM = cur ? mask1 : mask0;
    uint32_t* const newM = cur ? mask0 : mask1;
    __syncthreads();  // sampling reads done
    if (lane == 0) {
      chosenM[(uint32_t)newNode >> 5] |= 1u << (newNode & 31);  // chosen |= new
      cnts[cur ^ 1] = 0;
    }
    for (int i = lane; i < NW; i += 64) { adjM[i] = 0u; newM[i] = 0u; }
    __syncthreads();
    if (lane < DEG) {
      const int c = neighbors[(size_t)newNode * DEG + lane];
      adjList[lane] = c;
      atomicOr(&adjM[(uint32_t)c >> 5], 1u << (c & 31));
    }
    __syncthreads();
    // (a) retained old candidates: reference semantics ((v - chosen) + adj) > 0 in f32
    for (int i = lane; i < cnt; i += 64) {
      const int   c = lst[cur][i];
      const float v = val[cur][i];
      const float ch = ((chosenM[(uint32_t)c >> 5] >> (c & 31)) & 1u) ? 1.0f : 0.0f;
      const float ad = ((adjM[(uint32_t)c >> 5]    >> (c & 31)) & 1u) ? 1.0f : 0.0f;
      if ((v - ch) + ad > 0.0f) {
        const int p = atomicAdd(&cnts[cur ^ 1], 1);
        if (p < MAXC) { lst[cur ^ 1][p] = c; val[cur ^ 1][p] = 1.0f; }
        atomicOr(&newM[(uint32_t)c >> 5], 1u << (c & 31));
      }
    }
    // (b) fresh neighbors of new: add iff not already a candidate and not chosen
    //     (disjoint from (a)'s c-set, so no barrier needed between the phases)
    if (lane < DEG) {
      const int c = adjList[lane];
      const uint32_t w = (uint32_t)c >> 5, bit = 1u << (c & 31);
      const bool inOld = (oldM[w] >> (c & 31)) & 1u;
      const bool chb   = (chosenM[w] >> (c & 31)) & 1u;
      if (!inOld && !chb) {
        const uint32_t old = atomicOr(&newM[w], bit);
        if (!(old & bit)) {
          const int p = atomicAdd(&cnts[cur ^ 1], 1);
          if (p < MAXC) { lst[cur ^ 1][p] = c; val[cur ^ 1][p] = 1.0f; }
        }
      }
    }
    __syncthreads();
    cur ^= 1;
  }
  if (lane == 0) out[r * (T + 1)] = self;
}

}  // namespace

extern "C" void kernel_launch(void* const* d_in, const int* in_sizes, int n_in,
                              void* d_out, int out_size, void* d_ws, size_t ws_size,
                              hipStream_t stream) {
  const float* features  = (const float*)d_in[0];
  const float* W         = (const float*)d_in[1];
  const float* b         = (const float*)d_in[2];
  const int*   neighbors = (const int*)d_in[3];
  const int*   tindex    = (const int*)d_in[4];
  int* out = (int*)d_out;

  hipLaunchKernelGGL(walk_kernel, dim3(BB), dim3(64), 0, stream,
                     features, W, b, neighbors, tindex, out);
}

// Round 3
// 28.155 us; speedup vs baseline: 1.4275x; 1.4275x over previous
//
#include <hip/hip_runtime.h>
#include <cstdint>

namespace {

constexpr int N    = 20000;   // nodes
constexpr int D    = 128;     // feature dim
constexpr int DEG  = 32;      // neighbors per node
constexpr int BB   = 1024;    // batch
constexpr int T    = 8;       // walk_times
constexpr int NW   = (N + 31) / 32;  // 625 mask words
constexpr int MAXC = 384;     // candidate-list bound (true max 32 + 8*32 + 1 = 289)

__device__ __forceinline__ uint32_t rotl32(uint32_t x, int n) {
  return (x << n) | (x >> (32 - n));
}

// Threefry-2x32, 20 rounds (Random123 / JAX threefry2x32_p).
__device__ __forceinline__ void threefry2x32(uint32_t k0, uint32_t k1,
                                             uint32_t x0, uint32_t x1,
                                             uint32_t& o0, uint32_t& o1) {
  const uint32_t ks2 = k0 ^ k1 ^ 0x1BD11BDAu;
  x0 += k0; x1 += k1;
#define TF_ROUND(r) { x0 += x1; x1 = rotl32(x1, (r)); x1 ^= x0; }
  TF_ROUND(13) TF_ROUND(15) TF_ROUND(26) TF_ROUND(6)
  x0 += k1;  x1 += ks2 + 1u;
  TF_ROUND(17) TF_ROUND(29) TF_ROUND(16) TF_ROUND(24)
  x0 += ks2; x1 += k0 + 2u;
  TF_ROUND(13) TF_ROUND(15) TF_ROUND(26) TF_ROUND(6)
  x0 += k0;  x1 += k1 + 3u;
  TF_ROUND(17) TF_ROUND(29) TF_ROUND(16) TF_ROUND(24)
  x0 += k1;  x1 += ks2 + 4u;
  TF_ROUND(13) TF_ROUND(15) TF_ROUND(26) TF_ROUND(6)
  x0 += ks2; x1 += k0 + 5u;
#undef TF_ROUND
  o0 = x0; o1 = x1;
}

// Exact emulation of jax.random.gumbel's f32 pipeline (used only at step 0).
// JAX _uniform: mant = bits >> 9 (TOP 23 bits); u = mant*2^-23 (or f32 tiny);
// gumbel = -fl32(log( fl32(-log(u)) )); double log == correctly-rounded f32 log.
__device__ __forceinline__ float gumbel_f32(uint32_t bits) {
  const uint32_t mant = bits >> 9;
  const float u = (mant == 0u) ? 1.17549435e-38f
                               : (__uint_as_float(0x3F800000u | mant) - 1.0f);
  const float inner = -(float)log((double)u);
  return -(float)log((double)inner);
}

__global__ __launch_bounds__(64)
void walk_kernel(const float* __restrict__ features,
                 const float* __restrict__ W,
                 const float* __restrict__ bptr,
                 const int*   __restrict__ neighbors,
                 const int*   __restrict__ train_index,
                 int* __restrict__ out)
{
  __shared__ uint32_t candM[NW];    // candidate membership (incremental)
  __shared__ uint32_t chosenM[NW];  // chosen/visited (monotone)
  __shared__ uint32_t adjM[NW];     // neighbors-of-new (incrementally cleared)
  __shared__ int      lst[2][MAXC];
  __shared__ float    val[2][MAXC];
  __shared__ int      cnts[2];
  __shared__ uint32_t skey[T][2];

  const int r    = blockIdx.x;
  const int lane = threadIdx.x;
  const int self = train_index[r];
  const uint32_t rN = (uint32_t)(r * N);

  for (int i = lane; i < NW; i += 64) { candM[i] = 0u; chosenM[i] = 0u; adjM[i] = 0u; }

  // Step keys: jax.random.split(key(42), 8), partitionable threefry.
  if (lane < T) {
    uint32_t o0, o1;
    threefry2x32(0u, 42u, 0u, (uint32_t)lane, o0, o1);
    skey[lane][0] = o0; skey[lane][1] = o1;
  }
  if (lane == 0) { cnts[0] = 0; cnts[1] = 0; }
  __syncthreads();

  // ---- step-0 scores: s_j = relu((sx + sy_j) + b) ----
  const float bval = bptr[0];
  const float* frow = features + (size_t)self * D;
  float acc = frow[lane] * W[lane] + frow[lane + 64] * W[lane + 64];
  for (int m = 1; m < 64; m <<= 1) acc += __shfl_xor(acc, m);
  const float sx = acc;   // identical across lanes

  int   nbj  = -1;
  float sval = 0.0f;
  if (lane < DEG) {
    nbj = neighbors[(size_t)self * DEG + lane];
    const float* g  = features + (size_t)nbj * D;
    const float* wy = W + D;
    float a = 0.0f;
    for (int d = 0; d < D; d += 4) {
      const float4 f = *reinterpret_cast<const float4*>(g + d);
      const float4 w = *reinterpret_cast<const float4*>(wy + d);
      a += f.x * w.x; a += f.y * w.y; a += f.z * w.z; a += f.w * w.w;
    }
    sval = fmaxf((sx + a) + bval, 0.0f);
  }
  // build step-0 candidate list: {c != self : s_c > 0}, dedup via candM
  if (lane < DEG && nbj != self && sval > 0.0f) {
    const uint32_t w = (uint32_t)nbj >> 5, bit = 1u << (nbj & 31);
    const uint32_t old = atomicOr(&candM[w], bit);
    if (!(old & bit)) {
      const int p = atomicAdd(&cnts[0], 1);
      if (p < MAXC) { lst[0][p] = nbj; val[0][p] = sval; }
    }
  }
  __syncthreads();
  if (lane == 0) {
    chosenM[(uint32_t)self >> 5] |= 1u << (self & 31);   // chosen = self_oh
    if (cnts[0] == 0) {  // pre-scan fallback mutates the carry: candi = self_oh
      lst[0][0] = self; val[0][0] = 1.0f; cnts[0] = 1;
      candM[(uint32_t)self >> 5] |= 1u << (self & 31);
    }
  }
  __syncthreads();

  int cur = 0;
  int prevW = 0;          // (lane<32) adjM word this lane set last step
  for (int k = 0; k < T; ++k) {
    const int cnt = cnts[cur];
    const uint32_t kk0 = skey[k][0], kk1 = skey[k][1];
    int newNode;
    if (cnt == 0) {
      // in-step fallback: p = self_oh, argmax trivially self (carry still updates)
      newNode = self;
    } else if (k == 0) {
      // scored step: v = log(s) + gumbel, exact f32 pipeline (<=32 candidates)
      float bestV = -__builtin_huge_valf();
      int   bestC = 0x7FFFFFFF;
      for (int i = lane; i < cnt; i += 64) {
        const int c = lst[cur][i];
        uint32_t o0, o1;
        threefry2x32(kk0, kk1, 0u, rN + (uint32_t)c, o0, o1);
        const float gmb = gumbel_f32(o0 ^ o1);
        const float lp  = (float)log((double)val[cur][i]);
        const float v   = lp + gmb;
        if (v > bestV || (v == bestV && c < bestC)) { bestV = v; bestC = c; }
      }
      for (int m = 1; m < 64; m <<= 1) {
        const float ov = __shfl_xor(bestV, m);
        const int   oc = __shfl_xor(bestC, m);
        if (ov > bestV || (ov == bestV && oc < bestC)) { bestV = ov; bestC = oc; }
      }
      newNode = bestC;
    } else {
      // steps >=1: logp == 0 for all candidates, and gumbel is strictly
      // monotone in the top-23-bit mantissa -> argmax(g) == argmax(mant),
      // ties (equal mant) -> smallest index, matching jnp.argmax.
      uint32_t bestK = 0u;
      int      bestC = 0x7FFFFFFF;
      for (int i = lane; i < cnt; i += 64) {
        const int c = lst[cur][i];
        uint32_t o0, o1;
        threefry2x32(kk0, kk1, 0u, rN + (uint32_t)c, o0, o1);
        const uint32_t key = (o0 ^ o1) >> 9;
        if (key > bestK || (key == bestK && c < bestC)) { bestK = key; bestC = c; }
      }
      for (int m = 1; m < 64; m <<= 1) {
        const uint32_t ok = __shfl_xor(bestK, m);
        const int      oc = __shfl_xor(bestC, m);
        if (ok > bestK || (ok == bestK && oc < bestC)) { bestK = ok; bestC = oc; }
      }
      newNode = bestC;
    }

    // issue next neighbor row load early; latency hides under mask maintenance
    int nb = 0;
    if (lane < DEG) nb = neighbors[(size_t)newNode * DEG + lane];

    if (lane == 0) {
      out[r * (T + 1) + k + 1] = newNode;
      chosenM[(uint32_t)newNode >> 5] |= 1u << (newNode & 31);  // chosen |= new
      cnts[cur ^ 1] = 0;
    }
    __syncthreads();  // sampling reads of lst/val done; cnts reset visible

    if (k > 0 && lane < DEG) adjM[prevW] = 0u;  // incremental clear (dup words ok)
    __syncthreads();
    if (lane < DEG) {
      prevW = (int)((uint32_t)nb >> 5);
      atomicOr(&adjM[prevW], 1u << (nb & 31));
    }
    __syncthreads();  // adjM built

    // (a) retained old candidates: reference f32 semantics ((v - ch) + ad) > 0
    for (int i = lane; i < cnt; i += 64) {
      const int      c   = lst[cur][i];
      const float    v   = val[cur][i];
      const uint32_t w   = (uint32_t)c >> 5, bit = 1u << (c & 31);
      const float    ch  = (chosenM[w] & bit) ? 1.0f : 0.0f;
      const float    ad  = (adjM[w]    & bit) ? 1.0f : 0.0f;
      if ((v - ch) + ad > 0.0f) {
        const int p = atomicAdd(&cnts[cur ^ 1], 1);
        if (p < MAXC) { lst[cur ^ 1][p] = c; val[cur ^ 1][p] = 1.0f; }
      } else {
        atomicAnd(&candM[w], ~bit);  // left the candidate set
      }
    }
    __syncthreads();  // (a)'s candM updates visible to (b)

    // (b) fresh adj members: add iff not already candidate and not chosen.
    // (dropped-in-(a) c with ad=1 implies ch=1, so no re-add conflict)
    if (lane < DEG) {
      const uint32_t w = (uint32_t)nb >> 5, bit = 1u << (nb & 31);
      if (!(chosenM[w] & bit) && !(candM[w] & bit)) {
        const uint32_t old = atomicOr(&candM[w], bit);
        if (!(old & bit)) {
          const int p = atomicAdd(&cnts[cur ^ 1], 1);
          if (p < MAXC) { lst[cur ^ 1][p] = nb; val[cur ^ 1][p] = 1.0f; }
        }
      }
    }
    __syncthreads();  // new list complete before next sampling
    cur ^= 1;
  }
  if (lane == 0) out[r * (T + 1)] = self;
}

}  // namespace

extern "C" void kernel_launch(void* const* d_in, const int* in_sizes, int n_in,
                              void* d_out, int out_size, void* d_ws, size_t ws_size,
                              hipStream_t stream) {
  const float* features  = (const float*)d_in[0];
  const float* W         = (const float*)d_in[1];
  const float* b         = (const float*)d_in[2];
  const int*   neighbors = (const int*)d_in[3];
  const int*   tindex    = (const int*)d_in[4];
  int* out = (int*)d_out;

  hipLaunchKernelGGL(walk_kernel, dim3(BB), dim3(64), 0, stream,
                     features, W, b, neighbors, tindex, out);
}